// Round 15
// baseline (136.574 us; speedup 1.0000x reference)
//
#include <hip/hip_runtime.h>
#include <hip/hip_bf16.h>
#include <stdint.h>

#define D_IN   1024
#define D_OUT  1024
#define NHEAD  16
#define HDIM   64
#define SEQ    2048
#define BATCH  2
#define M_TOT  (BATCH*SEQ)   // 4096

typedef __attribute__((ext_vector_type(8)))  short bfx8;   // 8 bf16
typedef __attribute__((ext_vector_type(4)))  short bfx4;   // 4 bf16
typedef __attribute__((ext_vector_type(4)))  float fx4;
typedef __attribute__((ext_vector_type(16))) float fx16;
typedef unsigned short u16;
typedef unsigned int   u32;

__device__ __forceinline__ u16 f2bf(float f) {
    u32 u = __builtin_bit_cast(u32, f);
    u32 r = (u + 0x7FFFu + ((u >> 16) & 1u)) >> 16;   // RNE
    return (u16)r;
}
__device__ __forceinline__ float bf2f(u16 v) {
    u32 u = (u32)v << 16;
    return __builtin_bit_cast(float, u);
}

__device__ __forceinline__ u32 cvtpk(float lo, float hi) {
    u32 r;
    asm("v_cvt_pk_bf16_f32 %0, %1, %2" : "=v"(r) : "v"(lo), "v"(hi));
    return r;
}

// async global -> LDS, 16B per lane. LDS dest = wave-uniform base + lane*16.
__device__ __forceinline__ void gload16(const u16* g, u16* l) {
    __builtin_amdgcn_global_load_lds(
        (const __attribute__((address_space(1))) void*)g,
        (__attribute__((address_space(3))) void*)l, 16, 0, 0);
}

// ---------------- x fp32 -> bf16 ----------------
__global__ void k_conv_x(const float* __restrict__ x, u16* __restrict__ xb) {
    int i = blockIdx.x * 256 + threadIdx.x;
    const float4* s = reinterpret_cast<const float4*>(x);
    float4 a = s[2*i], b = s[2*i+1];
    uint4 o;
    o.x = (u32)f2bf(a.x) | ((u32)f2bf(a.y) << 16);
    o.y = (u32)f2bf(a.z) | ((u32)f2bf(a.w) << 16);
    o.z = (u32)f2bf(b.x) | ((u32)f2bf(b.y) << 16);
    o.w = (u32)f2bf(b.z) | ((u32)f2bf(b.w) << 16);
    reinterpret_cast<uint4*>(xb)[i] = o;
}

// ------------- W fp32 -> bf16, transposed (Wt[n][k] = W[k][n]) -------------
// Wq additionally pre-scaled by 1/sqrt(HDIM)=0.125 so scores come out pre-scaled.
__global__ void k_conv_wt(const float* __restrict__ Wq, const float* __restrict__ Wk,
                          const float* __restrict__ Wv, const float* __restrict__ Wo,
                          u16* __restrict__ wt) {
    __shared__ float tile[32][33];
    int wsel = blockIdx.z;
    const float* W = (wsel == 0) ? Wq : (wsel == 1) ? Wk : (wsel == 2) ? Wv : Wo;
    const float scale = (wsel == 0) ? 0.125f : 1.0f;
    u16* dst = wt + (size_t)wsel * D_IN * D_OUT;
    int r0 = blockIdx.y * 32, c0 = blockIdx.x * 32;
    int tx = threadIdx.x & 31, ty = threadIdx.x >> 5;
    #pragma unroll
    for (int k = 0; k < 4; k++) {
        int i = ty + k * 8;
        tile[i][tx] = W[(size_t)(r0 + i) * D_OUT + c0 + tx];
    }
    __syncthreads();
    #pragma unroll
    for (int k = 0; k < 4; k++) {
        int i = ty + k * 8;
        dst[(size_t)(c0 + i) * D_IN + r0 + tx] = f2bf(tile[tx][i] * scale);
    }
}

// ---------------- 128x128 GEMM (m97 structure, round-9 version) ----------------
// MODE 0: qkv fused (N=3072): Q,K head-split [proj][b*h][s][d] bf16;
//         V written TRANSPOSED: [b*h][d][s] bf16.
// MODE 1: oproj: write f32 out[m][n] = acc + bias[n]
template<int MODE>
__global__ __launch_bounds__(256) void k_gemm128(const u16* __restrict__ A,
                                                 const u16* __restrict__ Bt,
                                                 const float* __restrict__ bias,
                                                 u16* __restrict__ outb,
                                                 float* __restrict__ outf) {
    __shared__ u16 aL[128][32];
    __shared__ u16 bL[128][32];
    const int K = 1024;
    const int nb = blockIdx.x * 128, mb = blockIdx.y * 128;
    const int t = threadIdx.x, lane = t & 63, w = t >> 6;
    const int wr = w >> 1, wc = w & 1;
    const int li = lane & 15, lg = lane >> 4;
    const int srow = lane >> 2, schunk = (lane & 3) * 8;

    fx4 acc[4][4];
    #pragma unroll
    for (int i = 0; i < 4; i++)
        #pragma unroll
        for (int j = 0; j < 4; j++) acc[i][j] = fx4{0.f, 0.f, 0.f, 0.f};

    const u16* aBase = A  + (size_t)(mb + w * 32 + srow) * K + schunk;
    const u16* bBase = Bt + (size_t)(nb + w * 32 + srow) * K + schunk;

    for (int kb = 0; kb < K; kb += 32) {
        #pragma unroll
        for (int c = 0; c < 2; c++) {
            gload16(aBase + (size_t)c * 16 * K + kb, &aL[w * 32 + c * 16][0]);
            gload16(bBase + (size_t)c * 16 * K + kb, &bL[w * 32 + c * 16][0]);
        }
        __syncthreads();
        bfx8 af[4], bf[4];
        #pragma unroll
        for (int mi = 0; mi < 4; mi++)
            af[mi] = *reinterpret_cast<const bfx8*>(&aL[wr * 64 + mi * 16 + li][lg * 8]);
        #pragma unroll
        for (int ni = 0; ni < 4; ni++)
            bf[ni] = *reinterpret_cast<const bfx8*>(&bL[wc * 64 + ni * 16 + li][lg * 8]);
        #pragma unroll
        for (int mi = 0; mi < 4; mi++)
            #pragma unroll
            for (int ni = 0; ni < 4; ni++)
                acc[mi][ni] = __builtin_amdgcn_mfma_f32_16x16x32_bf16(af[mi], bf[ni], acc[mi][ni], 0, 0, 0);
        __syncthreads();
    }

    #pragma unroll
    for (int mi = 0; mi < 4; mi++) {
        #pragma unroll
        for (int ni = 0; ni < 4; ni++) {
            const int n = nb + wc * 64 + ni * 16 + li;
            const int m0 = mb + wr * 64 + mi * 16 + lg * 4;
            if (MODE == 0) {
                const int proj = n >> 10, h = (n >> 6) & 15, d = n & 63;
                const int b = m0 >> 11, s0 = m0 & 2047;
                if (proj == 2) {
                    // V transposed: [b*h][d][s], 4 consecutive s -> one 8B store
                    u16* op = outb + (size_t)2 * M_TOT * D_OUT +
                              ((size_t)(b * NHEAD + h) * HDIM + d) * SEQ + s0;
                    bfx4 pk = {(short)f2bf(acc[mi][ni][0]), (short)f2bf(acc[mi][ni][1]),
                               (short)f2bf(acc[mi][ni][2]), (short)f2bf(acc[mi][ni][3])};
                    *reinterpret_cast<bfx4*>(op) = pk;
                } else {
                    u16* op = outb + (size_t)proj * M_TOT * D_OUT;
                    #pragma unroll
                    for (int r = 0; r < 4; r++)
                        op[((size_t)(b * NHEAD + h) * SEQ + s0 + r) * HDIM + d] =
                            f2bf(acc[mi][ni][r]);
                }
            } else {
                const float bv = bias[n];
                #pragma unroll
                for (int r = 0; r < 4; r++)
                    outf[(size_t)(m0 + r) * D_OUT + n] = acc[mi][ni][r] + bv;
            }
        }
    }
}

// ---------------- causal flash attention (K staged, V direct from L2) -----------
// Round-14 structure (kv-split heavy blocks, 2 waves x 32 q-rows) with V
// staging REMOVED: V^T is L2-resident (256KB/head) and consumed ~300cyc after
// the exp phase starts, so per-lane global loads issued at loop top have
// natural latency slack (guide Common-mistake #7). LDS halves 32->16KB ->
// ~8 resident blocks/CU (was 5): double the stall-hiding wave pool.
// K stays LDS-staged (shared by both waves), XOR-swizzled.
__global__ __launch_bounds__(128, 4) void k_attn(const u16* __restrict__ Q,
                                                 const u16* __restrict__ Kp,
                                                 const u16* __restrict__ Vt,
                                                 u16* __restrict__ ctx,
                                                 u16* __restrict__ o1,
                                                 float* __restrict__ l0,
                                                 float* __restrict__ l1) {
    __shared__ u16 kbuf[2][64][64];   // K tile [kv][d], swizzled slots (16KB)

    const int g = blockIdx.x;                    // 0..1535, heaviest first
    int qi, part, m;
    const bool heavy = (g < 1024);
    if (heavy) {                                  // qi 31..16, 2 parts x 32 bh
        qi = 31 - (g >> 6);
        part = (g >> 5) & 1;
        m = g & 31;
    } else {                                      // qi 15..0, 1 part x 32 bh
        int j = g - 1024;
        qi = 15 - (j >> 5);
        part = 0;
        m = j & 31;
    }
    const int bh = (m & 7) * 4 + (m >> 3);        // 4 heads per XCD
    const int nt = qi + 1;
    int t0, t1;
    if (heavy) { int h1 = nt >> 1; t0 = part ? h1 : 0; t1 = part ? nt : h1; }
    else       { t0 = 0; t1 = nt; }
    const int ntL = t1 - t0;                      // <= 16

    const size_t base = (size_t)bh * SEQ * HDIM;  // == bh*HDIM*SEQ
    const int t = threadIdx.x, lane = t & 63, w = t >> 6;   // w 0..1
    const int l31 = lane & 31, hi = lane >> 5;
    const int srow = lane >> 3;                   // 0..7 within 8-row slab
    const int ts = (lane & 7) ^ srow;             // pre-swizzled source chunk
    const int bq = bh >> 4, hh = bh & 15;
    const int swz = (l31 & 7) * 8;                // read-side XOR (u16 units)
    const int qwb = qi * 64 + w * 32;
    const int qg  = qwb + l31;                    // this lane's q row

    // stage one 64-kv K tile (8KB); 4 gload16 per wave
    auto stage = [&](int bi, int kvb) {
        #pragma unroll
        for (int i = 0; i < 4; i++) {
            const int rb = w * 32 + i * 8;
            gload16(Kp + base + (size_t)(kvb + rb + srow) * HDIM + ts * 8,
                    &kbuf[bi][rb][0]);
        }
    };

    bfx8 qf[4];
    #pragma unroll
    for (int dc = 0; dc < 4; dc++)
        qf[dc] = *reinterpret_cast<const bfx8*>(
            &Q[base + (size_t)qg * HDIM + dc * 16 + hi * 8]);
    fx16 cacc[2];
    #pragma unroll
    for (int dt = 0; dt < 2; dt++)
        #pragma unroll
        for (int r = 0; r < 16; r++) cacc[dt][r] = 0.f;
    float lsum = 0.f;

    stage(0, t0 * 64);

    for (int tt = 0; tt < ntL; tt++) {
        const int ti = t0 + tt, kvb = ti * 64;
        // ---- V fragments for THIS tile: per-lane 16B from L2-resident V^T ----
        bfx8 vr[2][4];
        #pragma unroll
        for (int dt = 0; dt < 2; dt++)
            #pragma unroll
            for (int c = 0; c < 4; c++)
                vr[dt][c] = *reinterpret_cast<const bfx8*>(
                    &Vt[base + (size_t)(dt * 32 + l31) * SEQ + kvb + c * 16 + hi * 8]);
        if (tt + 1 < ntL) {
            stage((tt + 1) & 1, (ti + 1) * 64);
            // outstanding: 4 old K + 8 V + 4 new K; wait old K only
            asm volatile("s_waitcnt vmcnt(12)" ::: "memory");
        } else {
            asm volatile("s_waitcnt vmcnt(8)" ::: "memory");   // 8 V still in flight
        }
        __builtin_amdgcn_s_barrier();
        __builtin_amdgcn_sched_barrier(0);
        const int bi = tt & 1;
        // ---- S^T = K · Q^T (rows=kv, cols=q) ----
        fx16 sc[2];
        #pragma unroll
        for (int s = 0; s < 2; s++) {
            #pragma unroll
            for (int r = 0; r < 16; r++) sc[s][r] = 0.f;
            #pragma unroll
            for (int dc = 0; dc < 4; dc++) {
                bfx8 kf = *reinterpret_cast<const bfx8*>(
                    &kbuf[bi][s * 32 + l31][(dc * 16 + hi * 8) ^ swz]);
                sc[s] = __builtin_amdgcn_mfma_f32_32x32x16_bf16(kf, qf[dc], sc[s], 0, 0, 0);
            }
        }
        // causal mask (diagonal tile only; pre-scaled scores)
        if (kvb + 63 > qwb) {
            #pragma unroll
            for (int s = 0; s < 2; s++)
                #pragma unroll
                for (int r = 0; r < 16; r++) {
                    int kvg = kvb + s * 32 + (r & 3) + 8 * (r >> 2) + 4 * hi;
                    if (kvg > qg) sc[s][r] = -1e30f;
                }
        }
        // P = exp(S), row-sum
        float ps = 0.f;
        #pragma unroll
        for (int s = 0; s < 2; s++)
            #pragma unroll
            for (int r = 0; r < 16; r++) {
                float pv = __expf(sc[s][r]);
                sc[s][r] = pv;
                ps += pv;
            }
        lsum += ps;
        // ---- pack P to bf16, lane-pair exchange, PV (V from registers) ----
        #pragma unroll
        for (int c = 0; c < 4; c++) {          // kv chunk of 16
            const int s = c >> 1, rb = (c & 1) * 8;
            u32 a0 = cvtpk(sc[s][rb + 0], sc[s][rb + 1]);
            u32 a1 = cvtpk(sc[s][rb + 2], sc[s][rb + 3]);
            u32 b0 = cvtpk(sc[s][rb + 4], sc[s][rb + 5]);
            u32 b1 = cvtpk(sc[s][rb + 6], sc[s][rb + 7]);
            u32 X0 = hi ? a0 : b0, X1 = hi ? a1 : b1;
            u32 Y0 = (u32)__shfl_xor((int)X0, 32);
            u32 Y1 = (u32)__shfl_xor((int)X1, 32);
            uint4 pw;
            pw.x = hi ? Y0 : a0;
            pw.y = hi ? Y1 : a1;
            pw.z = hi ? b0 : Y0;
            pw.w = hi ? b1 : Y1;
            bfx8 pf = __builtin_bit_cast(bfx8, pw);
            #pragma unroll
            for (int dt = 0; dt < 2; dt++)
                cacc[dt] = __builtin_amdgcn_mfma_f32_32x32x16_bf16(pf, vr[dt][c], cacc[dt], 0, 0, 0);
        }
        asm volatile("s_waitcnt lgkmcnt(0)" ::: "memory");
        __builtin_amdgcn_s_barrier();
    }

    float ltot = lsum + __shfl_xor(lsum, 32);
    if (!heavy) {
        float linv = 1.0f / ltot;
        #pragma unroll
        for (int r = 0; r < 16; r++) {
            const int qpat = (r & 3) + 8 * (r >> 2) + 4 * hi;
            float rl = __shfl(linv, qpat);
            const int q = qwb + qpat;
            #pragma unroll
            for (int dt = 0; dt < 2; dt++)
                ctx[((size_t)(bq * SEQ + q)) * D_OUT + hh * HDIM + dt * 32 + l31] =
                    f2bf(cacc[dt][r] * rl);
        }
    } else {
        const int qi16 = qi - 16;
        const int lidx = ((qi16 * 32 + bh) * 64) + w * 32 + l31;
        if (hi == 0) { (part ? l1 : l0)[lidx] = ltot; }
        #pragma unroll
        for (int r = 0; r < 16; r++) {
            const int qpat = (r & 3) + 8 * (r >> 2) + 4 * hi;
            const int q = qwb + qpat;
            #pragma unroll
            for (int dt = 0; dt < 2; dt++) {
                const int d = dt * 32 + l31;
                u16 val = f2bf(cacc[dt][r]);
                if (part == 0)
                    ctx[((size_t)(bq * SEQ + q)) * D_OUT + hh * HDIM + d] = val;
                else
                    o1[(((size_t)(qi16 * 32 + bh) * 64) + w * 32 + qpat) * 64 + d] = val;
            }
        }
    }
}

// ---------------- combine heavy partials: ctx = (O0+O1)/(l0+l1) ----------------
__global__ void k_comb(u16* __restrict__ ctx, const u16* __restrict__ o1,
                       const float* __restrict__ l0, const float* __restrict__ l1) {
    int i = blockIdx.x * 256 + threadIdx.x;      // 262144 threads, 8 d-els each
    const int d    = (i & 7) * 8;
    const int qrow = (i >> 3) & 63;
    const int bi_  = i >> 9;                     // [qi16*32 + bh], 0..511
    const int bh   = bi_ & 31, qi16 = bi_ >> 5;
    const int bq = bh >> 4, hh = bh & 15;
    const int token = bq * SEQ + (16 + qi16) * 64 + qrow;
    const size_t cidx = (size_t)token * D_OUT + hh * HDIM + d;
    const size_t oidx = ((size_t)(bi_ * 64 + qrow)) * 64 + d;
    const float linv = 1.0f / (l0[bi_ * 64 + qrow] + l1[bi_ * 64 + qrow]);
    bfx8 a = *reinterpret_cast<const bfx8*>(&ctx[cidx]);
    bfx8 b = *reinterpret_cast<const bfx8*>(&o1[oidx]);
    bfx8 o;
    #pragma unroll
    for (int j = 0; j < 8; j++)
        o[j] = (short)f2bf((bf2f((u16)a[j]) + bf2f((u16)b[j])) * linv);
    *reinterpret_cast<bfx8*>(&ctx[cidx]) = o;
}

extern "C" void kernel_launch(void* const* d_in, const int* in_sizes, int n_in,
                              void* d_out, int out_size, void* d_ws, size_t ws_size,
                              hipStream_t stream) {
    const float* x  = (const float*)d_in[0];
    const float* Wq = (const float*)d_in[1];
    const float* Wk = (const float*)d_in[2];
    const float* Wv = (const float*)d_in[3];
    const float* Wo = (const float*)d_in[4];
    const float* bo = (const float*)d_in[5];
    float* out = (float*)d_out;

    char* ws = (char*)d_ws;
    u16* xb   = (u16*)(ws);                    //  8 MiB: x bf16 (dead after gemm0;
                                               //  reused for attn partials)
    u16* wt   = (u16*)(ws + (8u << 20));       //  8 MiB: W transposed bf16
    u16* qkvb = (u16*)(ws + (16u << 20));      // 24 MiB: Q,K [bh][s][d]; V^T [bh][d][s]
    u16* ctxb = (u16*)(ws + (40u << 20));      //  8 MiB: ctx bf16

    // attn partial scratch inside xb region (xb consumed before attn runs)
    u16*   o1p = (u16*)(ws);                   // 4 MiB: part1 O bf16
    float* l0p = (float*)(ws + (4u << 20));    // 128 KiB
    float* l1p = (float*)(ws + (4u << 20) + (128u << 10));

    const u16* Qb  = qkvb;
    const u16* Kb  = qkvb + (size_t)M_TOT * D_OUT;
    const u16* Vtb = qkvb + (size_t)2 * M_TOT * D_OUT;

    k_conv_x <<<2048, 256, 0, stream>>>(x, xb);
    k_conv_wt<<<dim3(32, 32, 4), 256, 0, stream>>>(Wq, Wk, Wv, Wo, wt);
    k_gemm128<0><<<dim3(24, 32), 256, 0, stream>>>(xb, wt, nullptr, qkvb, nullptr);
    k_attn   <<<dim3(1536), 128, 0, stream>>>(Qb, Kb, Vtb, ctxb, o1p, l0p, l1p);
    k_comb   <<<1024, 256, 0, stream>>>(ctxb, o1p, l0p, l1p);
    k_gemm128<1><<<dim3(8, 32), 256, 0, stream>>>(
        ctxb, wt + (size_t)3 * D_IN * D_OUT, bo, nullptr, out);
}

// Round 16
// 115.597 us; speedup vs baseline: 1.1815x; 1.1815x over previous
//
#include <hip/hip_runtime.h>
#include <hip/hip_bf16.h>
#include <stdint.h>

#define D_IN   1024
#define D_OUT  1024
#define NHEAD  16
#define HDIM   64
#define SEQ    2048
#define BATCH  2
#define M_TOT  (BATCH*SEQ)   // 4096

typedef __attribute__((ext_vector_type(8)))  short bfx8;   // 8 bf16
typedef __attribute__((ext_vector_type(4)))  short bfx4;   // 4 bf16
typedef __attribute__((ext_vector_type(4)))  float fx4;
typedef __attribute__((ext_vector_type(16))) float fx16;
typedef unsigned short u16;
typedef unsigned int   u32;

__device__ __forceinline__ u16 f2bf(float f) {
    u32 u = __builtin_bit_cast(u32, f);
    u32 r = (u + 0x7FFFu + ((u >> 16) & 1u)) >> 16;   // RNE
    return (u16)r;
}
__device__ __forceinline__ float bf2f(u16 v) {
    u32 u = (u32)v << 16;
    return __builtin_bit_cast(float, u);
}

__device__ __forceinline__ u32 cvtpk(float lo, float hi) {
    u32 r;
    asm("v_cvt_pk_bf16_f32 %0, %1, %2" : "=v"(r) : "v"(lo), "v"(hi));
    return r;
}

// async global -> LDS, 16B per lane. LDS dest = wave-uniform base + lane*16.
__device__ __forceinline__ void gload16(const u16* g, u16* l) {
    __builtin_amdgcn_global_load_lds(
        (const __attribute__((address_space(1))) void*)g,
        (__attribute__((address_space(3))) void*)l, 16, 0, 0);
}

// ---------------- x fp32 -> bf16 ----------------
__global__ void k_conv_x(const float* __restrict__ x, u16* __restrict__ xb) {
    int i = blockIdx.x * 256 + threadIdx.x;
    const float4* s = reinterpret_cast<const float4*>(x);
    float4 a = s[2*i], b = s[2*i+1];
    uint4 o;
    o.x = (u32)f2bf(a.x) | ((u32)f2bf(a.y) << 16);
    o.y = (u32)f2bf(a.z) | ((u32)f2bf(a.w) << 16);
    o.z = (u32)f2bf(b.x) | ((u32)f2bf(b.y) << 16);
    o.w = (u32)f2bf(b.z) | ((u32)f2bf(b.w) << 16);
    reinterpret_cast<uint4*>(xb)[i] = o;
}

// ------------- W fp32 -> bf16, transposed (Wt[n][k] = W[k][n]) -------------
// Wq additionally pre-scaled by 1/sqrt(HDIM)=0.125 so scores come out pre-scaled.
__global__ void k_conv_wt(const float* __restrict__ Wq, const float* __restrict__ Wk,
                          const float* __restrict__ Wv, const float* __restrict__ Wo,
                          u16* __restrict__ wt) {
    __shared__ float tile[32][33];
    int wsel = blockIdx.z;
    const float* W = (wsel == 0) ? Wq : (wsel == 1) ? Wk : (wsel == 2) ? Wv : Wo;
    const float scale = (wsel == 0) ? 0.125f : 1.0f;
    u16* dst = wt + (size_t)wsel * D_IN * D_OUT;
    int r0 = blockIdx.y * 32, c0 = blockIdx.x * 32;
    int tx = threadIdx.x & 31, ty = threadIdx.x >> 5;
    #pragma unroll
    for (int k = 0; k < 4; k++) {
        int i = ty + k * 8;
        tile[i][tx] = W[(size_t)(r0 + i) * D_OUT + c0 + tx];
    }
    __syncthreads();
    #pragma unroll
    for (int k = 0; k < 4; k++) {
        int i = ty + k * 8;
        dst[(size_t)(c0 + i) * D_IN + r0 + tx] = f2bf(tile[tx][i] * scale);
    }
}

// ---------------- 128x128 GEMM (m97 structure, round-9 version) ----------------
// MODE 0: qkv fused (N=3072): Q,K head-split [proj][b*h][s][d] bf16;
//         V written TRANSPOSED: [b*h][d][s] bf16.
// MODE 1: oproj: write f32 out[m][n] = acc + bias[n]
template<int MODE>
__global__ __launch_bounds__(256) void k_gemm128(const u16* __restrict__ A,
                                                 const u16* __restrict__ Bt,
                                                 const float* __restrict__ bias,
                                                 u16* __restrict__ outb,
                                                 float* __restrict__ outf) {
    __shared__ u16 aL[128][32];
    __shared__ u16 bL[128][32];
    const int K = 1024;
    const int nb = blockIdx.x * 128, mb = blockIdx.y * 128;
    const int t = threadIdx.x, lane = t & 63, w = t >> 6;
    const int wr = w >> 1, wc = w & 1;
    const int li = lane & 15, lg = lane >> 4;
    const int srow = lane >> 2, schunk = (lane & 3) * 8;

    fx4 acc[4][4];
    #pragma unroll
    for (int i = 0; i < 4; i++)
        #pragma unroll
        for (int j = 0; j < 4; j++) acc[i][j] = fx4{0.f, 0.f, 0.f, 0.f};

    const u16* aBase = A  + (size_t)(mb + w * 32 + srow) * K + schunk;
    const u16* bBase = Bt + (size_t)(nb + w * 32 + srow) * K + schunk;

    for (int kb = 0; kb < K; kb += 32) {
        #pragma unroll
        for (int c = 0; c < 2; c++) {
            gload16(aBase + (size_t)c * 16 * K + kb, &aL[w * 32 + c * 16][0]);
            gload16(bBase + (size_t)c * 16 * K + kb, &bL[w * 32 + c * 16][0]);
        }
        __syncthreads();
        bfx8 af[4], bf[4];
        #pragma unroll
        for (int mi = 0; mi < 4; mi++)
            af[mi] = *reinterpret_cast<const bfx8*>(&aL[wr * 64 + mi * 16 + li][lg * 8]);
        #pragma unroll
        for (int ni = 0; ni < 4; ni++)
            bf[ni] = *reinterpret_cast<const bfx8*>(&bL[wc * 64 + ni * 16 + li][lg * 8]);
        #pragma unroll
        for (int mi = 0; mi < 4; mi++)
            #pragma unroll
            for (int ni = 0; ni < 4; ni++)
                acc[mi][ni] = __builtin_amdgcn_mfma_f32_16x16x32_bf16(af[mi], bf[ni], acc[mi][ni], 0, 0, 0);
        __syncthreads();
    }

    #pragma unroll
    for (int mi = 0; mi < 4; mi++) {
        #pragma unroll
        for (int ni = 0; ni < 4; ni++) {
            const int n = nb + wc * 64 + ni * 16 + li;
            const int m0 = mb + wr * 64 + mi * 16 + lg * 4;
            if (MODE == 0) {
                const int proj = n >> 10, h = (n >> 6) & 15, d = n & 63;
                const int b = m0 >> 11, s0 = m0 & 2047;
                if (proj == 2) {
                    // V transposed: [b*h][d][s], 4 consecutive s -> one 8B store
                    u16* op = outb + (size_t)2 * M_TOT * D_OUT +
                              ((size_t)(b * NHEAD + h) * HDIM + d) * SEQ + s0;
                    bfx4 pk = {(short)f2bf(acc[mi][ni][0]), (short)f2bf(acc[mi][ni][1]),
                               (short)f2bf(acc[mi][ni][2]), (short)f2bf(acc[mi][ni][3])};
                    *reinterpret_cast<bfx4*>(op) = pk;
                } else {
                    u16* op = outb + (size_t)proj * M_TOT * D_OUT;
                    #pragma unroll
                    for (int r = 0; r < 4; r++)
                        op[((size_t)(b * NHEAD + h) * SEQ + s0 + r) * HDIM + d] =
                            f2bf(acc[mi][ni][r]);
                }
            } else {
                const float bv = bias[n];
                #pragma unroll
                for (int r = 0; r < 4; r++)
                    outf[(size_t)(m0 + r) * D_OUT + n] = acc[mi][ni][r] + bv;
            }
        }
    }
}

// ---------------- causal flash attention (8-wave, 256-row q-tile) ----------------
// m214 geometry: 512 threads = 8 waves, each owning 32 q-rows -> 256-row q-tile
// sharing ONE staged K/V tile (staging traffic / instructions amortized 4x vs
// the 2-wave version: 2 gload16 per wave per tile). Inner per-wave math is the
// verified round-13/14 code. Wave-level causal skip inside the barrier pair.
// Heavy q-tiles (qt>=4) are kv-split across 2 blocks (addition-combine, no
// max-tracking); parts <=16 tiles. Grid 384, heaviest-first.
// K [bh][s][d], V^T [bh][d][s] staged via global_load_lds with XOR-swizzle on
// the SOURCE chunk; ds_read applies the same XOR.
__global__ __launch_bounds__(512, 2) void k_attn(const u16* __restrict__ Q,
                                                 const u16* __restrict__ Kp,
                                                 const u16* __restrict__ Vt,
                                                 u16* __restrict__ ctx,
                                                 u16* __restrict__ o1,
                                                 float* __restrict__ l0,
                                                 float* __restrict__ l1) {
    __shared__ u16 kbuf[2][64][64];   // K tile [kv][d], swizzled slots (16KB)
    __shared__ u16 vbuf[2][64][64];   // V^T tile [d][kv], swizzled slots (16KB)

    // pp -> (qt, part): heaviest first. qt>=4 split x2.
    static const __constant__ signed char QT[12]   = {7,7,6,6,5,5,4,4,3,2,1,0};
    static const __constant__ signed char PART[12] = {0,1,0,1,0,1,0,1,0,0,0,0};

    const int g  = blockIdx.x;                   // 0..383
    const int m  = g & 31, pp = g >> 5;          // pp 0..11
    const int bh = (m & 7) * 4 + (m >> 3);       // 4 heads per XCD
    const int qt = QT[pp], part = PART[pp];
    const bool heavy = (qt >= 4);
    const int nt = 4 * qt + 4;                   // kv tiles for this q-tile
    int t0, t1;
    if (heavy) { int h1 = nt >> 1; t0 = part ? h1 : 0; t1 = part ? nt : h1; }
    else       { t0 = 0; t1 = nt; }
    const int ntL = t1 - t0;                     // <= 16

    const size_t base = (size_t)bh * SEQ * HDIM; // == bh*HDIM*SEQ
    const int t = threadIdx.x, lane = t & 63, w = t >> 6;   // w 0..7
    const int l31 = lane & 31, hi = lane >> 5;
    const int srow = lane >> 3;                  // 0..7 within this wave's slab
    const int ts = (lane & 7) ^ srow;            // pre-swizzled source chunk
    const int bq = bh >> 4, hh = bh & 15;
    const int swz = (l31 & 7) * 8;               // read-side XOR (u16 units)
    const int qwb = qt * 256 + w * 32;
    const int qg  = qwb + l31;                   // this lane's q row

    // stage one 64-kv tile (K 8KB + V^T 8KB); 2 gload16 per wave (8 waves)
    auto stage = [&](int bi, int kvb) {
        const int rb = w * 8;                    // this wave's 8-row slab
        gload16(Kp + base + (size_t)(kvb + rb + srow) * HDIM + ts * 8,
                &kbuf[bi][rb][0]);
        gload16(Vt + base + (size_t)(rb + srow) * SEQ + kvb + ts * 8,
                &vbuf[bi][rb][0]);
    };

    bfx8 qf[4];
    #pragma unroll
    for (int dc = 0; dc < 4; dc++)
        qf[dc] = *reinterpret_cast<const bfx8*>(
            &Q[base + (size_t)qg * HDIM + dc * 16 + hi * 8]);
    fx16 cacc[2];
    #pragma unroll
    for (int dt = 0; dt < 2; dt++)
        #pragma unroll
        for (int r = 0; r < 16; r++) cacc[dt][r] = 0.f;
    float lsum = 0.f;

    stage(0, t0 * 64);

    for (int tt = 0; tt < ntL; tt++) {
        const int ti = t0 + tt, kvb = ti * 64;
        if (tt + 1 < ntL) {
            stage((tt + 1) & 1, (ti + 1) * 64);
            // wait own stage(tt) (2 older loads); stage(tt+1) stays in flight
            asm volatile("s_waitcnt vmcnt(2)" ::: "memory");
        } else {
            asm volatile("s_waitcnt vmcnt(0)" ::: "memory");
        }
        __builtin_amdgcn_s_barrier();
        __builtin_amdgcn_sched_barrier(0);
        const int bi = tt & 1;
        if (kvb <= qwb + 31) {                   // wave-level causal skip
            // ---- S^T = K · Q^T (rows=kv, cols=q) ----
            fx16 sc[2];
            #pragma unroll
            for (int s = 0; s < 2; s++) {
                #pragma unroll
                for (int r = 0; r < 16; r++) sc[s][r] = 0.f;
                #pragma unroll
                for (int dc = 0; dc < 4; dc++) {
                    bfx8 kf = *reinterpret_cast<const bfx8*>(
                        &kbuf[bi][s * 32 + l31][(dc * 16 + hi * 8) ^ swz]);
                    sc[s] = __builtin_amdgcn_mfma_f32_32x32x16_bf16(kf, qf[dc], sc[s], 0, 0, 0);
                }
            }
            // causal mask (diagonal tile only; pre-scaled scores)
            if (kvb + 63 > qwb) {
                #pragma unroll
                for (int s = 0; s < 2; s++)
                    #pragma unroll
                    for (int r = 0; r < 16; r++) {
                        int kvg = kvb + s * 32 + (r & 3) + 8 * (r >> 2) + 4 * hi;
                        if (kvg > qg) sc[s][r] = -1e30f;
                    }
            }
            // P = exp(S), row-sum
            float ps = 0.f;
            #pragma unroll
            for (int s = 0; s < 2; s++)
                #pragma unroll
                for (int r = 0; r < 16; r++) {
                    float pv = __expf(sc[s][r]);
                    sc[s][r] = pv;
                    ps += pv;
                }
            lsum += ps;
            // ---- pack P to bf16, lane-pair exchange, PV ----
            #pragma unroll
            for (int c = 0; c < 4; c++) {          // kv chunk of 16
                const int s = c >> 1, rb_ = (c & 1) * 8;
                u32 a0 = cvtpk(sc[s][rb_ + 0], sc[s][rb_ + 1]);
                u32 a1 = cvtpk(sc[s][rb_ + 2], sc[s][rb_ + 3]);
                u32 b0 = cvtpk(sc[s][rb_ + 4], sc[s][rb_ + 5]);
                u32 b1 = cvtpk(sc[s][rb_ + 6], sc[s][rb_ + 7]);
                u32 X0 = hi ? a0 : b0, X1 = hi ? a1 : b1;
                u32 Y0 = (u32)__shfl_xor((int)X0, 32);
                u32 Y1 = (u32)__shfl_xor((int)X1, 32);
                uint4 pw;
                pw.x = hi ? Y0 : a0;
                pw.y = hi ? Y1 : a1;
                pw.z = hi ? b0 : Y0;
                pw.w = hi ? b1 : Y1;
                bfx8 pf = __builtin_bit_cast(bfx8, pw);
                #pragma unroll
                for (int dt = 0; dt < 2; dt++) {
                    bfx8 vf = *reinterpret_cast<const bfx8*>(
                        &vbuf[bi][dt * 32 + l31][(c * 16 + hi * 8) ^ swz]);
                    cacc[dt] = __builtin_amdgcn_mfma_f32_32x32x16_bf16(pf, vf, cacc[dt], 0, 0, 0);
                }
            }
        }
        asm volatile("s_waitcnt lgkmcnt(0)" ::: "memory");
        __builtin_amdgcn_s_barrier();
    }

    float ltot = lsum + __shfl_xor(lsum, 32);
    if (!heavy) {
        float linv = 1.0f / ltot;
        #pragma unroll
        for (int r = 0; r < 16; r++) {
            const int qpat = (r & 3) + 8 * (r >> 2) + 4 * hi;
            float rl = __shfl(linv, qpat);
            const int q = qwb + qpat;
            #pragma unroll
            for (int dt = 0; dt < 2; dt++)
                ctx[((size_t)(bq * SEQ + q)) * D_OUT + hh * HDIM + dt * 32 + l31] =
                    f2bf(cacc[dt][r] * rl);
        }
    } else {
        // partial write: O unnormalized (bf16) + per-row l (f32)
        const int qt4 = qt - 4;
        const int rbase = (qt4 * 32 + bh) * 256 + w * 32;
        if (hi == 0) { (part ? l1 : l0)[rbase + l31] = ltot; }
        #pragma unroll
        for (int r = 0; r < 16; r++) {
            const int qpat = (r & 3) + 8 * (r >> 2) + 4 * hi;
            const int q = qwb + qpat;
            #pragma unroll
            for (int dt = 0; dt < 2; dt++) {
                const int d = dt * 32 + l31;
                u16 val = f2bf(cacc[dt][r]);
                if (part == 0)
                    ctx[((size_t)(bq * SEQ + q)) * D_OUT + hh * HDIM + d] = val;
                else
                    o1[((size_t)(rbase + qpat)) * 64 + d] = val;
            }
        }
    }
}

// ---------------- combine heavy partials: ctx = (O0+O1)/(l0+l1) ----------------
// heavy rows: q in [1024, 2048) per bh; 4 qt-groups x 32 bh x 256 rows x 64 d.
__global__ void k_comb(u16* __restrict__ ctx, const u16* __restrict__ o1,
                       const float* __restrict__ l0, const float* __restrict__ l1) {
    int i = blockIdx.x * 256 + threadIdx.x;      // 262144 threads, 8 d-els each
    const int d    = (i & 7) * 8;
    const int qrow = (i >> 3) & 255;
    const int bi_  = i >> 11;                    // qt4*32 + bh, 0..127
    const int bh   = bi_ & 31, qt4 = bi_ >> 5;
    const int bq = bh >> 4, hh = bh & 15;
    const int token = bq * SEQ + (4 + qt4) * 256 + qrow;
    const size_t cidx = (size_t)token * D_OUT + hh * HDIM + d;
    const int ridx = bi_ * 256 + qrow;
    const size_t oidx = (size_t)ridx * 64 + d;
    const float linv = 1.0f / (l0[ridx] + l1[ridx]);
    bfx8 a = *reinterpret_cast<const bfx8*>(&ctx[cidx]);
    bfx8 b = *reinterpret_cast<const bfx8*>(&o1[oidx]);
    bfx8 o;
    #pragma unroll
    for (int j = 0; j < 8; j++)
        o[j] = (short)f2bf((bf2f((u16)a[j]) + bf2f((u16)b[j])) * linv);
    *reinterpret_cast<bfx8*>(&ctx[cidx]) = o;
}

extern "C" void kernel_launch(void* const* d_in, const int* in_sizes, int n_in,
                              void* d_out, int out_size, void* d_ws, size_t ws_size,
                              hipStream_t stream) {
    const float* x  = (const float*)d_in[0];
    const float* Wq = (const float*)d_in[1];
    const float* Wk = (const float*)d_in[2];
    const float* Wv = (const float*)d_in[3];
    const float* Wo = (const float*)d_in[4];
    const float* bo = (const float*)d_in[5];
    float* out = (float*)d_out;

    char* ws = (char*)d_ws;
    u16* xb   = (u16*)(ws);                    //  8 MiB: x bf16 (dead after gemm0;
                                               //  reused for attn partials)
    u16* wt   = (u16*)(ws + (8u << 20));       //  8 MiB: W transposed bf16
    u16* qkvb = (u16*)(ws + (16u << 20));      // 24 MiB: Q,K [bh][s][d]; V^T [bh][d][s]
    u16* ctxb = (u16*)(ws + (40u << 20));      //  8 MiB: ctx bf16

    // attn partial scratch inside xb region (xb consumed before attn runs)
    u16*   o1p = (u16*)(ws);                   // 4 MiB: part1 O bf16
    float* l0p = (float*)(ws + (4u << 20));    // 128 KiB
    float* l1p = (float*)(ws + (4u << 20) + (128u << 10));

    const u16* Qb  = qkvb;
    const u16* Kb  = qkvb + (size_t)M_TOT * D_OUT;
    const u16* Vtb = qkvb + (size_t)2 * M_TOT * D_OUT;

    k_conv_x <<<2048, 256, 0, stream>>>(x, xb);
    k_conv_wt<<<dim3(32, 32, 4), 256, 0, stream>>>(Wq, Wk, Wv, Wo, wt);
    k_gemm128<0><<<dim3(24, 32), 256, 0, stream>>>(xb, wt, nullptr, qkvb, nullptr);
    k_attn   <<<dim3(384), 512, 0, stream>>>(Qb, Kb, Vtb, ctxb, o1p, l0p, l1p);
    k_comb   <<<1024, 256, 0, stream>>>(ctxb, o1p, l0p, l1p);
    k_gemm128<1><<<dim3(8, 32), 256, 0, stream>>>(
        ctxb, wt + (size_t)3 * D_IN * D_OUT, bo, nullptr, out);
}

// Round 17
// 110.671 us; speedup vs baseline: 1.2341x; 1.0445x over previous
//
#include <hip/hip_runtime.h>
#include <hip/hip_bf16.h>
#include <stdint.h>

#define D_IN   1024
#define D_OUT  1024
#define NHEAD  16
#define HDIM   64
#define SEQ    2048
#define BATCH  2
#define M_TOT  (BATCH*SEQ)   // 4096

typedef __attribute__((ext_vector_type(8)))  short bfx8;   // 8 bf16
typedef __attribute__((ext_vector_type(4)))  short bfx4;   // 4 bf16
typedef __attribute__((ext_vector_type(4)))  float fx4;
typedef __attribute__((ext_vector_type(16))) float fx16;
typedef unsigned short u16;
typedef unsigned int   u32;

__device__ __forceinline__ u16 f2bf(float f) {
    u32 u = __builtin_bit_cast(u32, f);
    u32 r = (u + 0x7FFFu + ((u >> 16) & 1u)) >> 16;   // RNE
    return (u16)r;
}
__device__ __forceinline__ float bf2f(u16 v) {
    u32 u = (u32)v << 16;
    return __builtin_bit_cast(float, u);
}

__device__ __forceinline__ u32 cvtpk(float lo, float hi) {
    u32 r;
    asm("v_cvt_pk_bf16_f32 %0, %1, %2" : "=v"(r) : "v"(lo), "v"(hi));
    return r;
}

__device__ __forceinline__ float exp2x(float x) {   // 2^x, single v_exp_f32
    float r;
    asm("v_exp_f32 %0, %1" : "=v"(r) : "v"(x));
    return r;
}

// async global -> LDS, 16B per lane. LDS dest = wave-uniform base + lane*16.
__device__ __forceinline__ void gload16(const u16* g, u16* l) {
    __builtin_amdgcn_global_load_lds(
        (const __attribute__((address_space(1))) void*)g,
        (__attribute__((address_space(3))) void*)l, 16, 0, 0);
}

// ---------------- x fp32 -> bf16 ----------------
__global__ void k_conv_x(const float* __restrict__ x, u16* __restrict__ xb) {
    int i = blockIdx.x * 256 + threadIdx.x;
    const float4* s = reinterpret_cast<const float4*>(x);
    float4 a = s[2*i], b = s[2*i+1];
    uint4 o;
    o.x = (u32)f2bf(a.x) | ((u32)f2bf(a.y) << 16);
    o.y = (u32)f2bf(a.z) | ((u32)f2bf(a.w) << 16);
    o.z = (u32)f2bf(b.x) | ((u32)f2bf(b.y) << 16);
    o.w = (u32)f2bf(b.z) | ((u32)f2bf(b.w) << 16);
    reinterpret_cast<uint4*>(xb)[i] = o;
}

// ------------- W fp32 -> bf16, transposed (Wt[n][k] = W[k][n]) -------------
// Wq pre-scaled by 0.125*log2(e) so attention uses raw v_exp_f32 (2^x).
__global__ void k_conv_wt(const float* __restrict__ Wq, const float* __restrict__ Wk,
                          const float* __restrict__ Wv, const float* __restrict__ Wo,
                          u16* __restrict__ wt) {
    __shared__ float tile[32][33];
    int wsel = blockIdx.z;
    const float* W = (wsel == 0) ? Wq : (wsel == 1) ? Wk : (wsel == 2) ? Wv : Wo;
    const float scale = (wsel == 0) ? 0.125f * 1.4426950408889634f : 1.0f;
    u16* dst = wt + (size_t)wsel * D_IN * D_OUT;
    int r0 = blockIdx.y * 32, c0 = blockIdx.x * 32;
    int tx = threadIdx.x & 31, ty = threadIdx.x >> 5;
    #pragma unroll
    for (int k = 0; k < 4; k++) {
        int i = ty + k * 8;
        tile[i][tx] = W[(size_t)(r0 + i) * D_OUT + c0 + tx];
    }
    __syncthreads();
    #pragma unroll
    for (int k = 0; k < 4; k++) {
        int i = ty + k * 8;
        dst[(size_t)(c0 + i) * D_IN + r0 + tx] = f2bf(tile[tx][i] * scale);
    }
}

// ---------------- 128x128 GEMM (m97 structure) — QKV only ----------------
// Q,K head-split [proj][b*h][s][d] bf16; V written TRANSPOSED [b*h][d][s].
__global__ __launch_bounds__(256) void k_qkv(const u16* __restrict__ A,
                                             const u16* __restrict__ Bt,
                                             u16* __restrict__ outb) {
    __shared__ u16 aL[128][32];
    __shared__ u16 bL[128][32];
    const int K = 1024;
    const int nb = blockIdx.x * 128, mb = blockIdx.y * 128;
    const int t = threadIdx.x, lane = t & 63, w = t >> 6;
    const int wr = w >> 1, wc = w & 1;
    const int li = lane & 15, lg = lane >> 4;
    const int srow = lane >> 2, schunk = (lane & 3) * 8;

    fx4 acc[4][4];
    #pragma unroll
    for (int i = 0; i < 4; i++)
        #pragma unroll
        for (int j = 0; j < 4; j++) acc[i][j] = fx4{0.f, 0.f, 0.f, 0.f};

    const u16* aBase = A  + (size_t)(mb + w * 32 + srow) * K + schunk;
    const u16* bBase = Bt + (size_t)(nb + w * 32 + srow) * K + schunk;

    for (int kb = 0; kb < K; kb += 32) {
        #pragma unroll
        for (int c = 0; c < 2; c++) {
            gload16(aBase + (size_t)c * 16 * K + kb, &aL[w * 32 + c * 16][0]);
            gload16(bBase + (size_t)c * 16 * K + kb, &bL[w * 32 + c * 16][0]);
        }
        __syncthreads();
        bfx8 af[4], bf[4];
        #pragma unroll
        for (int mi = 0; mi < 4; mi++)
            af[mi] = *reinterpret_cast<const bfx8*>(&aL[wr * 64 + mi * 16 + li][lg * 8]);
        #pragma unroll
        for (int ni = 0; ni < 4; ni++)
            bf[ni] = *reinterpret_cast<const bfx8*>(&bL[wc * 64 + ni * 16 + li][lg * 8]);
        #pragma unroll
        for (int mi = 0; mi < 4; mi++)
            #pragma unroll
            for (int ni = 0; ni < 4; ni++)
                acc[mi][ni] = __builtin_amdgcn_mfma_f32_16x16x32_bf16(af[mi], bf[ni], acc[mi][ni], 0, 0, 0);
        __syncthreads();
    }

    #pragma unroll
    for (int mi = 0; mi < 4; mi++) {
        #pragma unroll
        for (int ni = 0; ni < 4; ni++) {
            const int n = nb + wc * 64 + ni * 16 + li;
            const int m0 = mb + wr * 64 + mi * 16 + lg * 4;
            const int proj = n >> 10, h = (n >> 6) & 15, d = n & 63;
            const int b = m0 >> 11, s0 = m0 & 2047;
            if (proj == 2) {
                u16* op = outb + (size_t)2 * M_TOT * D_OUT +
                          ((size_t)(b * NHEAD + h) * HDIM + d) * SEQ + s0;
                bfx4 pk = {(short)f2bf(acc[mi][ni][0]), (short)f2bf(acc[mi][ni][1]),
                           (short)f2bf(acc[mi][ni][2]), (short)f2bf(acc[mi][ni][3])};
                *reinterpret_cast<bfx4*>(op) = pk;
            } else {
                u16* op = outb + (size_t)proj * M_TOT * D_OUT;
                #pragma unroll
                for (int r = 0; r < 4; r++)
                    op[((size_t)(b * NHEAD + h) * SEQ + s0 + r) * HDIM + d] =
                        f2bf(acc[mi][ni][r]);
            }
        }
    }
}

// ---------------- output projection: 128(M) x 64(N) tiles ----------------
// grid (16,32) = 512 blocks = 2/CU (the old 128x128 gave 256 blocks = 1/CU,
// stripping the m97 structure of its co-resident-block overlap).
// 4 waves as 2x2: per-wave 64 rows x 32 cols (acc 4x2).
__global__ __launch_bounds__(256) void k_oproj(const u16* __restrict__ A,
                                               const u16* __restrict__ Bt,
                                               const float* __restrict__ bias,
                                               float* __restrict__ outf) {
    __shared__ u16 aL[128][32];
    __shared__ u16 bL[64][32];
    const int K = 1024;
    const int nb = blockIdx.x * 64, mb = blockIdx.y * 128;
    const int t = threadIdx.x, lane = t & 63, w = t >> 6;
    const int wr = w >> 1, wc = w & 1;
    const int li = lane & 15, lg = lane >> 4;
    const int srow = lane >> 2, schunk = (lane & 3) * 8;

    fx4 acc[4][2];
    #pragma unroll
    for (int i = 0; i < 4; i++)
        #pragma unroll
        for (int j = 0; j < 2; j++) acc[i][j] = fx4{0.f, 0.f, 0.f, 0.f};

    const u16* aBase = A  + (size_t)(mb + w * 32 + srow) * K + schunk;
    const u16* bBase = Bt + (size_t)(nb + w * 16 + srow) * K + schunk;

    for (int kb = 0; kb < K; kb += 32) {
        gload16(aBase + kb,          &aL[w * 32][0]);
        gload16(aBase + 16 * K + kb, &aL[w * 32 + 16][0]);
        gload16(bBase + kb,          &bL[w * 16][0]);
        __syncthreads();
        bfx8 af[4], bf[2];
        #pragma unroll
        for (int mi = 0; mi < 4; mi++)
            af[mi] = *reinterpret_cast<const bfx8*>(&aL[wr * 64 + mi * 16 + li][lg * 8]);
        #pragma unroll
        for (int ni = 0; ni < 2; ni++)
            bf[ni] = *reinterpret_cast<const bfx8*>(&bL[wc * 32 + ni * 16 + li][lg * 8]);
        #pragma unroll
        for (int mi = 0; mi < 4; mi++)
            #pragma unroll
            for (int ni = 0; ni < 2; ni++)
                acc[mi][ni] = __builtin_amdgcn_mfma_f32_16x16x32_bf16(af[mi], bf[ni], acc[mi][ni], 0, 0, 0);
        __syncthreads();
    }

    #pragma unroll
    for (int mi = 0; mi < 4; mi++) {
        #pragma unroll
        for (int ni = 0; ni < 2; ni++) {
            const int n = nb + wc * 32 + ni * 16 + li;
            const int m0 = mb + wr * 64 + mi * 16 + lg * 4;
            const float bv = bias[n];
            #pragma unroll
            for (int r = 0; r < 4; r++)
                outf[(size_t)(m0 + r) * D_OUT + n] = acc[mi][ni][r] + bv;
        }
    }
}

// ---------------- causal flash attention (8-wave, 256-row q-tile) ----------------
// Round-16 structure; only change: P = exp2(S) with log2e folded into Wq scale
// (drops 32 v_mul per tile from the exp dep chain).
__global__ __launch_bounds__(512, 2) void k_attn(const u16* __restrict__ Q,
                                                 const u16* __restrict__ Kp,
                                                 const u16* __restrict__ Vt,
                                                 u16* __restrict__ ctx,
                                                 u16* __restrict__ o1,
                                                 float* __restrict__ l0,
                                                 float* __restrict__ l1) {
    __shared__ u16 kbuf[2][64][64];   // K tile [kv][d], swizzled slots (16KB)
    __shared__ u16 vbuf[2][64][64];   // V^T tile [d][kv], swizzled slots (16KB)

    // pp -> (qt, part): heaviest first. qt>=4 split x2.
    static const __constant__ signed char QT[12]   = {7,7,6,6,5,5,4,4,3,2,1,0};
    static const __constant__ signed char PART[12] = {0,1,0,1,0,1,0,1,0,0,0,0};

    const int g  = blockIdx.x;                   // 0..383
    const int m  = g & 31, pp = g >> 5;          // pp 0..11
    const int bh = (m & 7) * 4 + (m >> 3);       // 4 heads per XCD
    const int qt = QT[pp], part = PART[pp];
    const bool heavy = (qt >= 4);
    const int nt = 4 * qt + 4;                   // kv tiles for this q-tile
    int t0, t1;
    if (heavy) { int h1 = nt >> 1; t0 = part ? h1 : 0; t1 = part ? nt : h1; }
    else       { t0 = 0; t1 = nt; }
    const int ntL = t1 - t0;                     // <= 16

    const size_t base = (size_t)bh * SEQ * HDIM; // == bh*HDIM*SEQ
    const int t = threadIdx.x, lane = t & 63, w = t >> 6;   // w 0..7
    const int l31 = lane & 31, hi = lane >> 5;
    const int srow = lane >> 3;                  // 0..7 within this wave's slab
    const int ts = (lane & 7) ^ srow;            // pre-swizzled source chunk
    const int bq = bh >> 4, hh = bh & 15;
    const int swz = (l31 & 7) * 8;               // read-side XOR (u16 units)
    const int qwb = qt * 256 + w * 32;
    const int qg  = qwb + l31;                   // this lane's q row

    // stage one 64-kv tile (K 8KB + V^T 8KB); 2 gload16 per wave (8 waves)
    auto stage = [&](int bi, int kvb) {
        const int rb = w * 8;                    // this wave's 8-row slab
        gload16(Kp + base + (size_t)(kvb + rb + srow) * HDIM + ts * 8,
                &kbuf[bi][rb][0]);
        gload16(Vt + base + (size_t)(rb + srow) * SEQ + kvb + ts * 8,
                &vbuf[bi][rb][0]);
    };

    bfx8 qf[4];
    #pragma unroll
    for (int dc = 0; dc < 4; dc++)
        qf[dc] = *reinterpret_cast<const bfx8*>(
            &Q[base + (size_t)qg * HDIM + dc * 16 + hi * 8]);
    fx16 cacc[2];
    #pragma unroll
    for (int dt = 0; dt < 2; dt++)
        #pragma unroll
        for (int r = 0; r < 16; r++) cacc[dt][r] = 0.f;
    float lsum = 0.f;

    stage(0, t0 * 64);

    for (int tt = 0; tt < ntL; tt++) {
        const int ti = t0 + tt, kvb = ti * 64;
        if (tt + 1 < ntL) {
            stage((tt + 1) & 1, (ti + 1) * 64);
            asm volatile("s_waitcnt vmcnt(2)" ::: "memory");
        } else {
            asm volatile("s_waitcnt vmcnt(0)" ::: "memory");
        }
        __builtin_amdgcn_s_barrier();
        __builtin_amdgcn_sched_barrier(0);
        const int bi = tt & 1;
        if (kvb <= qwb + 31) {                   // wave-level causal skip
            // ---- S^T = K · Q^T (rows=kv, cols=q) ----
            fx16 sc[2];
            #pragma unroll
            for (int s = 0; s < 2; s++) {
                #pragma unroll
                for (int r = 0; r < 16; r++) sc[s][r] = 0.f;
                #pragma unroll
                for (int dc = 0; dc < 4; dc++) {
                    bfx8 kf = *reinterpret_cast<const bfx8*>(
                        &kbuf[bi][s * 32 + l31][(dc * 16 + hi * 8) ^ swz]);
                    sc[s] = __builtin_amdgcn_mfma_f32_32x32x16_bf16(kf, qf[dc], sc[s], 0, 0, 0);
                }
            }
            // causal mask (diagonal tile only; scores pre-scaled by 0.125*log2e)
            if (kvb + 63 > qwb) {
                #pragma unroll
                for (int s = 0; s < 2; s++)
                    #pragma unroll
                    for (int r = 0; r < 16; r++) {
                        int kvg = kvb + s * 32 + (r & 3) + 8 * (r >> 2) + 4 * hi;
                        if (kvg > qg) sc[s][r] = -1e30f;
                    }
            }
            // P = 2^S, row-sum
            float ps = 0.f;
            #pragma unroll
            for (int s = 0; s < 2; s++)
                #pragma unroll
                for (int r = 0; r < 16; r++) {
                    float pv = exp2x(sc[s][r]);
                    sc[s][r] = pv;
                    ps += pv;
                }
            lsum += ps;
            // ---- pack P to bf16, lane-pair exchange, PV ----
            #pragma unroll
            for (int c = 0; c < 4; c++) {          // kv chunk of 16
                const int s = c >> 1, rb_ = (c & 1) * 8;
                u32 a0 = cvtpk(sc[s][rb_ + 0], sc[s][rb_ + 1]);
                u32 a1 = cvtpk(sc[s][rb_ + 2], sc[s][rb_ + 3]);
                u32 b0 = cvtpk(sc[s][rb_ + 4], sc[s][rb_ + 5]);
                u32 b1 = cvtpk(sc[s][rb_ + 6], sc[s][rb_ + 7]);
                u32 X0 = hi ? a0 : b0, X1 = hi ? a1 : b1;
                u32 Y0 = (u32)__shfl_xor((int)X0, 32);
                u32 Y1 = (u32)__shfl_xor((int)X1, 32);
                uint4 pw;
                pw.x = hi ? Y0 : a0;
                pw.y = hi ? Y1 : a1;
                pw.z = hi ? b0 : Y0;
                pw.w = hi ? b1 : Y1;
                bfx8 pf = __builtin_bit_cast(bfx8, pw);
                #pragma unroll
                for (int dt = 0; dt < 2; dt++) {
                    bfx8 vf = *reinterpret_cast<const bfx8*>(
                        &vbuf[bi][dt * 32 + l31][(c * 16 + hi * 8) ^ swz]);
                    cacc[dt] = __builtin_amdgcn_mfma_f32_32x32x16_bf16(pf, vf, cacc[dt], 0, 0, 0);
                }
            }
        }
        asm volatile("s_waitcnt lgkmcnt(0)" ::: "memory");
        __builtin_amdgcn_s_barrier();
    }

    float ltot = lsum + __shfl_xor(lsum, 32);
    if (!heavy) {
        float linv = 1.0f / ltot;
        #pragma unroll
        for (int r = 0; r < 16; r++) {
            const int qpat = (r & 3) + 8 * (r >> 2) + 4 * hi;
            float rl = __shfl(linv, qpat);
            const int q = qwb + qpat;
            #pragma unroll
            for (int dt = 0; dt < 2; dt++)
                ctx[((size_t)(bq * SEQ + q)) * D_OUT + hh * HDIM + dt * 32 + l31] =
                    f2bf(cacc[dt][r] * rl);
        }
    } else {
        // partial write: O unnormalized (bf16) + per-row l (f32)
        const int qt4 = qt - 4;
        const int rbase = (qt4 * 32 + bh) * 256 + w * 32;
        if (hi == 0) { (part ? l1 : l0)[rbase + l31] = ltot; }
        #pragma unroll
        for (int r = 0; r < 16; r++) {
            const int qpat = (r & 3) + 8 * (r >> 2) + 4 * hi;
            const int q = qwb + qpat;
            #pragma unroll
            for (int dt = 0; dt < 2; dt++) {
                const int d = dt * 32 + l31;
                u16 val = f2bf(cacc[dt][r]);
                if (part == 0)
                    ctx[((size_t)(bq * SEQ + q)) * D_OUT + hh * HDIM + d] = val;
                else
                    o1[((size_t)(rbase + qpat)) * 64 + d] = val;
            }
        }
    }
}

// ---------------- combine heavy partials: ctx = (O0+O1)/(l0+l1) ----------------
__global__ void k_comb(u16* __restrict__ ctx, const u16* __restrict__ o1,
                       const float* __restrict__ l0, const float* __restrict__ l1) {
    int i = blockIdx.x * 256 + threadIdx.x;      // 262144 threads, 8 d-els each
    const int d    = (i & 7) * 8;
    const int qrow = (i >> 3) & 255;
    const int bi_  = i >> 11;                    // qt4*32 + bh, 0..127
    const int bh   = bi_ & 31, qt4 = bi_ >> 5;
    const int bq = bh >> 4, hh = bh & 15;
    const int token = bq * SEQ + (4 + qt4) * 256 + qrow;
    const size_t cidx = (size_t)token * D_OUT + hh * HDIM + d;
    const int ridx = bi_ * 256 + qrow;
    const size_t oidx = (size_t)ridx * 64 + d;
    const float linv = 1.0f / (l0[ridx] + l1[ridx]);
    bfx8 a = *reinterpret_cast<const bfx8*>(&ctx[cidx]);
    bfx8 b = *reinterpret_cast<const bfx8*>(&o1[oidx]);
    bfx8 o;
    #pragma unroll
    for (int j = 0; j < 8; j++)
        o[j] = (short)f2bf((bf2f((u16)a[j]) + bf2f((u16)b[j])) * linv);
    *reinterpret_cast<bfx8*>(&ctx[cidx]) = o;
}

extern "C" void kernel_launch(void* const* d_in, const int* in_sizes, int n_in,
                              void* d_out, int out_size, void* d_ws, size_t ws_size,
                              hipStream_t stream) {
    const float* x  = (const float*)d_in[0];
    const float* Wq = (const float*)d_in[1];
    const float* Wk = (const float*)d_in[2];
    const float* Wv = (const float*)d_in[3];
    const float* Wo = (const float*)d_in[4];
    const float* bo = (const float*)d_in[5];
    float* out = (float*)d_out;

    char* ws = (char*)d_ws;
    u16* xb   = (u16*)(ws);                    //  8 MiB: x bf16 (dead after qkv;
                                               //  reused for attn partials)
    u16* wt   = (u16*)(ws + (8u << 20));       //  8 MiB: W transposed bf16
    u16* qkvb = (u16*)(ws + (16u << 20));      // 24 MiB: Q,K [bh][s][d]; V^T [bh][d][s]
    u16* ctxb = (u16*)(ws + (40u << 20));      //  8 MiB: ctx bf16

    // attn partial scratch inside xb region (xb consumed before attn runs)
    u16*   o1p = (u16*)(ws);                   // 4 MiB: part1 O bf16
    float* l0p = (float*)(ws + (4u << 20));    // 128 KiB
    float* l1p = (float*)(ws + (4u << 20) + (128u << 10));

    const u16* Qb  = qkvb;
    const u16* Kb  = qkvb + (size_t)M_TOT * D_OUT;
    const u16* Vtb = qkvb + (size_t)2 * M_TOT * D_OUT;

    k_conv_x <<<2048, 256, 0, stream>>>(x, xb);
    k_conv_wt<<<dim3(32, 32, 4), 256, 0, stream>>>(Wq, Wk, Wv, Wo, wt);
    k_qkv    <<<dim3(24, 32), 256, 0, stream>>>(xb, wt, qkvb);
    k_attn   <<<dim3(384), 512, 0, stream>>>(Qb, Kb, Vtb, ctxb, o1p, l0p, l1p);
    k_comb   <<<1024, 256, 0, stream>>>(ctxb, o1p, l0p, l1p);
    k_oproj  <<<dim3(16, 32), 256, 0, stream>>>(
        ctxb, wt + (size_t)3 * D_IN * D_OUT, bo, out);
}